// Round 14
// baseline (531.708 us; speedup 1.0000x reference)
//
#include <hip/hip_runtime.h>
#include <stdint.h>

#define NLBL      4096
#define HALF_ROWS 8192
#define HALF_CNT  33554432u   // B*NL/2 = 2^25
#define TPB       512
#define GRID      2048
#define ITERS     4           // GRID*ITERS == 8192 row pairs

__device__ __forceinline__ uint32_t rotl32(uint32_t x, uint32_t r) {
    return __builtin_amdgcn_alignbit(x, x, 32u - r);
}

// JAX threefry2x32 with key (0, 42)  [jax.random.key(42)]
__device__ __forceinline__ void threefry2x32(uint32_t x0, uint32_t x1,
                                             uint32_t& o0, uint32_t& o1) {
    const uint32_t ks0 = 0u;
    const uint32_t ks1 = 42u;
    const uint32_t ks2 = 0x1BD11BDAu ^ ks0 ^ ks1;
    x0 += ks0; x1 += ks1;
#define TF_RND(r) x0 += x1; x1 = rotl32(x1, (r)); x1 ^= x0;
    TF_RND(13u) TF_RND(15u) TF_RND(26u) TF_RND(6u)
    x0 += ks1; x1 += ks2 + 1u;
    TF_RND(17u) TF_RND(29u) TF_RND(16u) TF_RND(24u)
    x0 += ks2; x1 += ks0 + 2u;
    TF_RND(13u) TF_RND(15u) TF_RND(26u) TF_RND(6u)
    x0 += ks0; x1 += ks1 + 3u;
    TF_RND(17u) TF_RND(29u) TF_RND(16u) TF_RND(24u)
    x0 += ks1; x1 += ks2 + 4u;
    TF_RND(13u) TF_RND(15u) TF_RND(26u) TF_RND(6u)
    x0 += ks2; x1 += ks0 + 5u;
#undef TF_RND
    o0 = x0; o1 = x1;
}

// Raw barrier: LDS-visibility drain only — vmcnt loads (our prefetch of the
// next row-pair) stay in flight across the barrier, unlike __syncthreads()
// which drains vmcnt(0) too.
#define LBAR() do { asm volatile("s_waitcnt lgkmcnt(0)" ::: "memory"); \
                    __builtin_amdgcn_s_barrier(); } while (0)

// JAX uniform = bitcast((bits>>9)|0x3F800000)-1.0 — strictly monotone in
// (bits>>9); we only ever COMPARE noise, so keep ub = bits>>9 as u32.

__global__ void __launch_bounds__(TPB)
warp_loss_main(const float* __restrict__ inputs,
               const float* __restrict__ targets,
               float* __restrict__ part)
{
    const int tid = threadIdx.x;
    const int wv  = tid >> 6;
    const int v4a = tid, v4b = tid + 512;

    __shared__ int                s_pos[2];
    __shared__ float              s_psc[2];
    __shared__ unsigned long long s_key[2][8];
    __shared__ unsigned int       s_cnt[8];
    __shared__ float              s_star[2];

    // Preload iteration 0 (4 input float4 + 4 target float4 per thread).
    float4 a0A, a0B, a1A, a1B, t0A, t0B, t1A, t1B;
    {
        const int rp = blockIdx.x;
        const float4* i0 = reinterpret_cast<const float4*>(inputs  + (size_t)rp * NLBL);
        const float4* i1 = reinterpret_cast<const float4*>(inputs  + (size_t)(rp + HALF_ROWS) * NLBL);
        const float4* g0 = reinterpret_cast<const float4*>(targets + (size_t)rp * NLBL);
        const float4* g1 = reinterpret_cast<const float4*>(targets + (size_t)(rp + HALF_ROWS) * NLBL);
        a0A = i0[v4a]; a0B = i0[v4b]; a1A = i1[v4a]; a1B = i1[v4b];
        t0A = g0[v4a]; t0B = g0[v4b]; t1A = g1[v4a]; t1B = g1[v4b];
    }

    #pragma unroll
    for (int it = 0; it < ITERS; ++it) {
        const int rp = blockIdx.x + it * GRID;
        const uint32_t cbase = (uint32_t)rp * NLBL;

        // Scores to named scalars (static indexing only — no scratch).
        const float sc0[8] = { a0A.x, a0A.y, a0A.z, a0A.w, a0B.x, a0B.y, a0B.z, a0B.w };
        const float sc1[8] = { a1A.x, a1A.y, a1A.z, a1A.w, a1B.x, a1B.y, a1B.z, a1B.w };

        // ---- threefry x8 (covers latency of the loads in flight) ----
        uint32_t ub0[8], ub1[8];
        #pragma unroll
        for (int kc = 0; kc < 2; ++kc) {
            #pragma unroll
            for (int j = 0; j < 4; ++j) {
                const uint32_t i = cbase + (uint32_t)((tid << 2) + j + (kc << 11));
                uint32_t o0, o1;
                threefry2x32(i, i + HALF_CNT, o0, o1);
                ub0[kc*4+j] = o0 >> 9;
                ub1[kc*4+j] = o1 >> 9;
            }
        }

        // ---- pos detect via select chain (consumes current targets) ----
        {
            const int cA = v4a << 2, cB = v4b << 2;
            const float tg0v[8] = { t0A.x, t0A.y, t0A.z, t0A.w, t0B.x, t0B.y, t0B.z, t0B.w };
            const float tg1v[8] = { t1A.x, t1A.y, t1A.z, t1A.w, t1B.x, t1B.y, t1B.z, t1B.w };
            int   idx0 = -1, idx1 = -1;
            float val0 = 0.0f, val1 = 0.0f;
            #pragma unroll
            for (int k = 0; k < 8; ++k) {
                const int c = (k < 4) ? (cA + k) : (cB + (k - 4));
                const bool h0 = tg0v[k] > 0.5f;
                const bool h1 = tg1v[k] > 0.5f;
                idx0 = h0 ? c : idx0;  val0 = h0 ? sc0[k] : val0;
                idx1 = h1 ? c : idx1;  val1 = h1 ? sc1[k] : val1;
            }
            if (idx0 >= 0) { s_pos[0] = idx0; s_psc[0] = val0; }
            if (idx1 >= 0) { s_pos[1] = idx1; s_psc[1] = val1; }
        }

        // ---- prefetch next row-pair (stays in flight across the raw barriers) ----
        float4 na0A, na0B, na1A, na1B, nt0A, nt0B, nt1A, nt1B;
        if (it + 1 < ITERS) {
            const int nrp = rp + GRID;
            const float4* i0 = reinterpret_cast<const float4*>(inputs  + (size_t)nrp * NLBL);
            const float4* i1 = reinterpret_cast<const float4*>(inputs  + (size_t)(nrp + HALF_ROWS) * NLBL);
            const float4* g0 = reinterpret_cast<const float4*>(targets + (size_t)nrp * NLBL);
            const float4* g1 = reinterpret_cast<const float4*>(targets + (size_t)(nrp + HALF_ROWS) * NLBL);
            na0A = i0[v4a]; na0B = i0[v4b]; na1A = i1[v4a]; na1B = i1[v4b];
            nt0A = g0[v4a]; nt0B = g0[v4b]; nt1A = g1[v4a]; nt1B = g1[v4b];
        }

        LBAR();   // barrier 1: s_pos / s_psc visible

        const int   pos0 = s_pos[0], pos1 = s_pos[1];
        const float psc0 = s_psc[0], psc1 = s_psc[1];

        // ---- phase 2: thread-local u32 argmax over hits, then one u64 pack.
        // hit = ((1+score)-pos_score) > 0 (exact JAX op order), c != pos.
        // Ascending c + strict > keeps min-c on equal noise. bu = ub*+1 (>0 <=> found).
        uint32_t bu0 = 0, bc0 = 0, bu1 = 0, bc1 = 0;
        #pragma unroll
        for (int k = 0; k < 8; ++k) {
            const int c = (tid << 2) + (k & 3) + ((k >= 4) ? 2048 : 0);
            const float m0 = (1.0f + sc0[k]) - psc0;
            const float m1 = (1.0f + sc1[k]) - psc1;
            if (c != pos0 && m0 > 0.0f) {
                const uint32_t u = ub0[k] + 1u;
                if (u > bu0) { bu0 = u; bc0 = (uint32_t)c; }
            }
            if (c != pos1 && m1 > 0.0f) {
                const uint32_t u = ub1[k] + 1u;
                if (u > bu1) { bu1 = u; bc1 = (uint32_t)c; }
            }
        }
        unsigned long long key0 = bu0 ? (((unsigned long long)bu0 << 12) |
                                         (unsigned long long)(4095u - bc0)) : 0ull;
        unsigned long long key1 = bu1 ? (((unsigned long long)bu1 << 12) |
                                         (unsigned long long)(4095u - bc1)) : 0ull;
        #pragma unroll
        for (int off = 32; off; off >>= 1) {
            const unsigned long long q0 = __shfl_xor(key0, off);
            const unsigned long long q1 = __shfl_xor(key1, off);
            if (q0 > key0) key0 = q0;
            if (q1 > key1) key1 = q1;
        }
        if ((tid & 63) == 0) { s_key[0][wv] = key0; s_key[1][wv] = key1; }

        LBAR();   // barrier 2: per-wave keys visible

        unsigned long long kk0 = s_key[0][0], kk1 = s_key[1][0];
        #pragma unroll
        for (int w = 1; w < 8; ++w) {
            if (s_key[0][w] > kk0) kk0 = s_key[0][w];
            if (s_key[1][w] > kk1) kk1 = s_key[1][w];
        }
        const int      c0  = (kk0 == 0ull) ? -1 : 4095 - (int)(kk0 & 0xFFFull);
        const int      c1  = (kk1 == 0ull) ? -1 : 4095 - (int)(kk1 & 0xFFFull);
        const uint32_t nb0 = (kk0 == 0ull) ? 0xFFFFFFFFu : (uint32_t)(kk0 >> 12) - 1u;
        const uint32_t nb1 = (kk1 == 0ull) ? 0xFFFFFFFFu : (uint32_t)(kk1 >> 12) - 1u;

        // ---- phase 3: rank(c*) count + winner-score publish ----
        uint32_t cnt = 0;
        #pragma unroll
        for (int k = 0; k < 8; ++k) {
            const int c = (tid << 2) + (k & 3) + ((k >= 4) ? 2048 : 0);
            if (c0 >= 0 && c != pos0 && (ub0[k] > nb0 || (ub0[k] == nb0 && c < c0))) cnt += 1u;
            if (c1 >= 0 && c != pos1 && (ub1[k] > nb1 || (ub1[k] == nb1 && c < c1))) cnt += 1u << 16;
            if (c == c0) s_star[0] = sc0[k];
            if (c == c1) s_star[1] = sc1[k];
        }
        #pragma unroll
        for (int off = 32; off; off >>= 1) cnt += __shfl_xor(cnt, off);
        if ((tid & 63) == 0) s_cnt[wv] = cnt;

        LBAR();   // barrier 3: counts + star scores visible

        if (tid == 0) {
            uint32_t tot = 0;
            #pragma unroll
            for (int w = 0; w < 8; ++w) tot += s_cnt[w];
            const int rank0 = (int)(tot & 0xFFFFu);
            const int rank1 = (int)(tot >> 16);
            float total = 0.0f;
            if (c0 >= 0 && rank0 < 64) {
                const float margin = (1.0f - psc0) + s_star[0];   // exact JAX loss op order
                total += logf(floorf(4095.0f / (float)(rank0 + 1))) * margin;
            }
            if (c1 >= 0 && rank1 < 64) {
                const float margin = (1.0f - psc1) + s_star[1];
                total += logf(floorf(4095.0f / (float)(rank1 + 1))) * margin;
            }
            part[rp] = total;
        }

        // rotate prefetched registers into place (SSA rename, no copies)
        if (it + 1 < ITERS) {
            a0A = na0A; a0B = na0B; a1A = na1A; a1B = na1B;
            t0A = nt0A; t0B = nt0B; t1A = nt1A; t1B = nt1B;
        }
    }
}

// 8192 partials -> single float.  One block, 1024 threads, 8 floats each.
__global__ void __launch_bounds__(1024)
warp_loss_reduce(const float* __restrict__ part, float* __restrict__ out)
{
    const int tid = threadIdx.x;
    const float4 a = reinterpret_cast<const float4*>(part)[tid];
    const float4 b = reinterpret_cast<const float4*>(part)[tid + 1024];
    float s = ((a.x + a.y) + (a.z + a.w)) + ((b.x + b.y) + (b.z + b.w));
    #pragma unroll
    for (int off = 32; off; off >>= 1) s += __shfl_xor(s, off);
    __shared__ float sm[16];
    if ((tid & 63) == 0) sm[tid >> 6] = s;
    __syncthreads();
    if (tid == 0) {
        float t = 0.0f;
        #pragma unroll
        for (int w = 0; w < 16; ++w) t += sm[w];
        out[0] = t;
    }
}

extern "C" void kernel_launch(void* const* d_in, const int* in_sizes, int n_in,
                              void* d_out, int out_size, void* d_ws, size_t ws_size,
                              hipStream_t stream) {
    const float* inputs  = (const float*)d_in[0];
    const float* targets = (const float*)d_in[1];
    float* out  = (float*)d_out;
    float* part = (float*)d_ws;          // 8192 floats = 32 KB scratch

    warp_loss_main  <<<dim3(GRID), dim3(TPB),  0, stream>>>(inputs, targets, part);
    warp_loss_reduce<<<dim3(1),    dim3(1024), 0, stream>>>(part, out);
}